// Round 3
// baseline (487.072 us; speedup 1.0000x reference)
//
#include <hip/hip_runtime.h>
#include <hip/hip_bf16.h>
#include <stdint.h>

typedef unsigned short u16;
typedef __attribute__((ext_vector_type(8))) short bf16x8;
typedef __attribute__((ext_vector_type(4))) float f32x4;

typedef __attribute__((address_space(3))) void lds_void;
typedef const __attribute__((address_space(1))) void gbl_void;

#define E_ 1024
#define H_ 16
#define D_ 64

static __device__ __forceinline__ u16 f2bf(float f) {
  union { __hip_bfloat16 b; u16 u; } cv;
  cv.b = __float2bfloat16(f);
  return cv.u;
}
static __device__ __forceinline__ float bf2f(u16 u) {
  union { __hip_bfloat16 b; u16 u; } cv;
  cv.u = u;
  return __bfloat162float(cv.b);
}

// ---------------- dtype detector ----------------
// Samples even u16s of `a`. True bf16 N(0,1) data: all |v| < 6.
// fp32 data: even u16s are low mantissa halves -> random bf16 bit patterns,
// almost surely (1 - ~4e-18) some |v| > 1e3 or NaN. flag=1 -> inputs are fp32.
__global__ __launch_bounds__(64) void k_detect(const u16* __restrict__ a,
                                               int* __restrict__ flag) {
  int lane = threadIdx.x;
  float v = bf2f(a[2 * lane]);
  bool bad = !(fabsf(v) < 1e3f);  // true also for NaN
  unsigned long long m = __ballot(bad);
  if (lane == 0) *flag = (m != 0ull) ? 1 : 0;
}

// ---------------- bias conversion (6 x 1024 -> bf16) ----------------
__global__ __launch_bounds__(256) void k_cvt_bias(
    const void* s0, const void* s1, const void* s2, const void* s3,
    const void* s4, const void* s5, u16* __restrict__ dst,
    const int* __restrict__ flag) {
  const void* srcs[6] = {s0, s1, s2, s3, s4, s5};
  int f = *flag;
  int z = blockIdx.y;
  int i = blockIdx.x * 256 + threadIdx.x;  // grid.x = 4 covers 1024
  u16 v = f ? f2bf(((const float*)srcs[z])[i]) : ((const u16*)srcs[z])[i];
  dst[z * 1024 + i] = v;
}

// ---------------- weight transpose (+ dtype convert) ----------------
// Wt[n][k] = W[k][n], output bf16 regardless of input dtype.
__global__ __launch_bounds__(256) void k_transpose_w(
    const void* a0, const void* a1, const void* a2, const void* a3,
    const void* a4, const void* a5,
    u16* d0, u16* d1, u16* d2, u16* d3, u16* d4, u16* d5,
    const int* __restrict__ flag) {
  __shared__ u16 tile[64][72];
  const void* srcs[6] = {a0, a1, a2, a3, a4, a5};
  u16* dsts[6] = {d0, d1, d2, d3, d4, d5};
  int f = *flag;
  int z = blockIdx.z;
  size_t sbase = (size_t)(blockIdx.y * 64) * E_ + blockIdx.x * 64;
  int t = threadIdx.x;
  int row = t >> 2, c4 = t & 3;
#pragma unroll
  for (int p = 0; p < 2; ++p) {
    int col = c4 * 8 + p * 32;
    size_t eo = sbase + (size_t)row * E_ + col;
    if (!f) {
      uint4 v = *(const uint4*)((const u16*)srcs[z] + eo);
      *(uint4*)(&tile[row][col]) = v;
    } else {
      const float* sf = (const float*)srcs[z] + eo;
      float4 x0 = *(const float4*)sf;
      float4 x1 = *(const float4*)(sf + 4);
      u16 tmp[8] = {f2bf(x0.x), f2bf(x0.y), f2bf(x0.z), f2bf(x0.w),
                    f2bf(x1.x), f2bf(x1.y), f2bf(x1.z), f2bf(x1.w)};
      *(uint4*)(&tile[row][col]) = *(uint4*)tmp;
    }
  }
  __syncthreads();
  u16* dst = dsts[z] + (size_t)(blockIdx.x * 64) * E_ + blockIdx.y * 64;
#pragma unroll
  for (int p = 0; p < 2; ++p) {
    int col = c4 * 8 + p * 32;
    u16 tmp[8];
#pragma unroll
    for (int i = 0; i < 8; ++i) tmp[i] = tile[col + i][row];
    *(uint4*)(dst + (size_t)row * E_ + col) = *(uint4*)tmp;
  }
}

// v: [B, N, E] bf16 (head h at cols h*64..) -> vt: [B*H, D, N] bf16
__global__ __launch_bounds__(256) void k_transpose_v(const u16* __restrict__ v,
                                                     u16* __restrict__ vt, int Nn) {
  __shared__ u16 tile[64][72];
  int z = blockIdx.y;  // b*H + h
  int b = z >> 4, h = z & 15;
  const u16* src = v + (size_t)b * Nn * E_ + (size_t)h * D_ + (size_t)(blockIdx.x * 64) * E_;
  u16* dst = vt + (size_t)z * D_ * Nn + blockIdx.x * 64;
  int t = threadIdx.x;
  int row = t >> 2, c4 = t & 3;
#pragma unroll
  for (int p = 0; p < 2; ++p) {
    int col = c4 * 8 + p * 32;
    uint4 q = *(const uint4*)(src + (size_t)row * E_ + col);
    *(uint4*)(&tile[row][col]) = q;
  }
  __syncthreads();
#pragma unroll
  for (int p = 0; p < 2; ++p) {
    int col = c4 * 8 + p * 32;
    u16 tmp[8];
#pragma unroll
    for (int i = 0; i < 8; ++i) tmp[i] = tile[col + i][row];
    *(uint4*)(dst + (size_t)row * Nn + col) = *(uint4*)tmp;
  }
}

// ---------------- GEMM: C[M,N] = A[M,K] @ Wt[N,K]^T + bias ----------------
// A: bf16 (internal) or fp32 (external input, when flag&&a_ext).
// C: bf16 (internal) or fp32 (final output, when flag&&out_ext).
// 128x128 tile, BK=32, 4 waves (2x2), fp32 accumulate.
__global__ __launch_bounds__(256) void k_gemm_bias(
    const void* __restrict__ A, const u16* __restrict__ Wt,
    const u16* __restrict__ bias, void* __restrict__ Cout,
    const int* __restrict__ flag, int a_ext, int out_ext, size_t coff,
    int M, int N, int K) {
  __shared__ u16 As[128 * 32];
  __shared__ u16 Bs[128 * 32];
  int f = *flag;
  bool f32in = (a_ext != 0) && (f != 0);
  bool f32out = (out_ext != 0) && (f != 0);

  int tid = threadIdx.x;
  int wave = tid >> 6, lane = tid & 63;
  int quad = lane >> 4, lrow = lane & 15;
  int wr = wave >> 1, wc = wave & 1;
  int m0 = blockIdx.y * 128, n0 = blockIdx.x * 128;

  f32x4 acc[4][4] = {};

  int srow = 32 * wave + (lane >> 2);
  int scol = (lane & 3) * 8;
  const u16* gB = Wt + (size_t)(n0 + srow) * K + scol;
  u16* lA = &As[(32 * wave) * 32];
  u16* lB = &Bs[(32 * wave) * 32];

  for (int k0 = 0; k0 < K; k0 += 32) {
    __syncthreads();
    if (!f32in) {
      const u16* gA = (const u16*)A + (size_t)(m0 + srow) * K + scol;
#pragma unroll
      for (int j = 0; j < 2; ++j)
        __builtin_amdgcn_global_load_lds((gbl_void*)(gA + (size_t)(16 * j) * K + k0),
                                         (lds_void*)(lA + 16 * j * 32), 16, 0, 0);
    } else {
      const float* Af = (const float*)A;
#pragma unroll
      for (int j = 0; j < 2; ++j) {
        const float* p = Af + (size_t)(m0 + srow + 16 * j) * K + k0 + scol;
        float4 x0 = *(const float4*)p;
        float4 x1 = *(const float4*)(p + 4);
        u16 tmp[8] = {f2bf(x0.x), f2bf(x0.y), f2bf(x0.z), f2bf(x0.w),
                      f2bf(x1.x), f2bf(x1.y), f2bf(x1.z), f2bf(x1.w)};
        *(uint4*)&As[(32 * wave + 16 * j + (lane >> 2)) * 32 + scol] = *(uint4*)tmp;
      }
    }
#pragma unroll
    for (int j = 0; j < 2; ++j)
      __builtin_amdgcn_global_load_lds((gbl_void*)(gB + (size_t)(16 * j) * K + k0),
                                       (lds_void*)(lB + 16 * j * 32), 16, 0, 0);
    __syncthreads();
    bf16x8 af[4], bfr[4];
#pragma unroll
    for (int i = 0; i < 4; ++i)
      af[i] = *(const bf16x8*)&As[(64 * wr + 16 * i + lrow) * 32 + 8 * quad];
#pragma unroll
    for (int j = 0; j < 4; ++j)
      bfr[j] = *(const bf16x8*)&Bs[(64 * wc + 16 * j + lrow) * 32 + 8 * quad];
#pragma unroll
    for (int i = 0; i < 4; ++i)
#pragma unroll
      for (int j = 0; j < 4; ++j)
        acc[i][j] = __builtin_amdgcn_mfma_f32_16x16x32_bf16(af[i], bfr[j], acc[i][j], 0, 0, 0);
  }

  float bv[4];
#pragma unroll
  for (int j = 0; j < 4; ++j) bv[j] = bf2f(bias[n0 + 64 * wc + 16 * j + lrow]);

  if (f32out) {
    float* Cf = (float*)Cout + coff;
#pragma unroll
    for (int i = 0; i < 4; ++i) {
      int row = m0 + 64 * wr + 16 * i + 4 * quad;
#pragma unroll
      for (int j = 0; j < 4; ++j) {
        int col = n0 + 64 * wc + 16 * j + lrow;
#pragma unroll
        for (int r = 0; r < 4; ++r)
          Cf[(size_t)(row + r) * N + col] = acc[i][j][r] + bv[j];
      }
    }
  } else {
    u16* Cb = (u16*)Cout + coff;
#pragma unroll
    for (int i = 0; i < 4; ++i) {
      int row = m0 + 64 * wr + 16 * i + 4 * quad;
#pragma unroll
      for (int j = 0; j < 4; ++j) {
        int col = n0 + 64 * wc + 16 * j + lrow;
#pragma unroll
        for (int r = 0; r < 4; ++r)
          Cb[(size_t)(row + r) * N + col] = f2bf(acc[i][j][r] + bv[j]);
      }
    }
  }
}

// ---------------- Fused dual-softmax attention (one side, all bf16) --------
// Out[l, d] = sum_s exp(scale * Q[l,:]·K[s,:]) * V[s,d] / sum_s exp(...)
__global__ __launch_bounds__(256) void k_attn(
    const u16* __restrict__ Q, const u16* __restrict__ Kk,
    const u16* __restrict__ VT, u16* __restrict__ Out, int Nq, int Nk) {
  __shared__ u16 Qs[64][72];
  __shared__ u16 Ks[64][72];
  __shared__ u16 Vs[64][72];
  __shared__ u16 Ps[64][72];
  int tid = threadIdx.x;
  int wave = tid >> 6, lane = tid & 63;
  int quad = lane >> 4, lrow = lane & 15;
  int z = blockIdx.y, b = z >> 4, h = z & 15;
  int l0 = blockIdx.x * 64;
  const u16* Qb = Q + (size_t)b * Nq * E_ + (size_t)h * D_;
  const u16* Kb = Kk + (size_t)b * Nk * E_ + (size_t)h * D_;
  const u16* Vb = VT + (size_t)z * D_ * Nk;

  {
    int row = tid >> 2, c8 = (tid & 3) * 8;
#pragma unroll
    for (int p = 0; p < 2; ++p) {
      uint4 v = *(const uint4*)(Qb + (size_t)(l0 + row) * E_ + c8 + p * 32);
      *(uint4*)(&Qs[row][c8 + p * 32]) = v;
    }
  }
  __syncthreads();
  bf16x8 qf0 = *(const bf16x8*)&Qs[16 * wave + lrow][8 * quad];
  bf16x8 qf1 = *(const bf16x8*)&Qs[16 * wave + lrow][32 + 8 * quad];

  f32x4 cacc[4] = {};
  float rsum[4] = {0.f, 0.f, 0.f, 0.f};
  const float scale = 0.125f;  // 1/sqrt(64)

  for (int s0 = 0; s0 < Nk; s0 += 64) {
    __syncthreads();
    {
      int row = tid >> 2, c8 = (tid & 3) * 8;
#pragma unroll
      for (int p = 0; p < 2; ++p) {
        uint4 kv = *(const uint4*)(Kb + (size_t)(s0 + row) * E_ + c8 + p * 32);
        *(uint4*)(&Ks[row][c8 + p * 32]) = kv;
        uint4 vv = *(const uint4*)(Vb + (size_t)row * Nk + s0 + c8 + p * 32);
        *(uint4*)(&Vs[row][c8 + p * 32]) = vv;
      }
    }
    __syncthreads();
#pragma unroll
    for (int j = 0; j < 4; ++j) {
      f32x4 sacc = {};
      bf16x8 kf0 = *(const bf16x8*)&Ks[16 * j + lrow][8 * quad];
      bf16x8 kf1 = *(const bf16x8*)&Ks[16 * j + lrow][32 + 8 * quad];
      sacc = __builtin_amdgcn_mfma_f32_16x16x32_bf16(qf0, kf0, sacc, 0, 0, 0);
      sacc = __builtin_amdgcn_mfma_f32_16x16x32_bf16(qf1, kf1, sacc, 0, 0, 0);
#pragma unroll
      for (int r = 0; r < 4; ++r) {
        float p = __expf(sacc[r] * scale);
        rsum[r] += p;
        Ps[16 * wave + 4 * quad + r][16 * j + lrow] = f2bf(p);
      }
    }
    __syncthreads();  // order Ps stores (C-layout) before A-layout reads
    bf16x8 pf0 = *(const bf16x8*)&Ps[16 * wave + lrow][8 * quad];
    bf16x8 pf1 = *(const bf16x8*)&Ps[16 * wave + lrow][32 + 8 * quad];
#pragma unroll
    for (int j = 0; j < 4; ++j) {
      bf16x8 vf0 = *(const bf16x8*)&Vs[16 * j + lrow][8 * quad];
      bf16x8 vf1 = *(const bf16x8*)&Vs[16 * j + lrow][32 + 8 * quad];
      cacc[j] = __builtin_amdgcn_mfma_f32_16x16x32_bf16(pf0, vf0, cacc[j], 0, 0, 0);
      cacc[j] = __builtin_amdgcn_mfma_f32_16x16x32_bf16(pf1, vf1, cacc[j], 0, 0, 0);
    }
  }

#pragma unroll
  for (int r = 0; r < 4; ++r) {
    float v = rsum[r];
    v += __shfl_xor(v, 1);
    v += __shfl_xor(v, 2);
    v += __shfl_xor(v, 4);
    v += __shfl_xor(v, 8);
    rsum[r] = v;
  }

  u16* Ob = Out + (size_t)b * Nq * E_ + (size_t)h * D_;
#pragma unroll
  for (int j = 0; j < 4; ++j) {
#pragma unroll
    for (int r = 0; r < 4; ++r) {
      float v = cacc[j][r] / rsum[r];
      Ob[(size_t)(l0 + 16 * wave + 4 * quad + r) * E_ + 16 * j + lrow] = f2bf(v);
    }
  }
}

extern "C" void kernel_launch(void* const* d_in, const int* in_sizes, int n_in,
                              void* d_out, int out_size, void* d_ws, size_t ws_size,
                              hipStream_t stream) {
  (void)in_sizes; (void)n_in; (void)out_size; (void)ws_size;
  u16* ws = (u16*)d_ws;
  const size_t MB1 = 1024u * 1024u;
  u16* wt0 = ws + 0 * MB1;   // Wa_qk^T
  u16* wt1 = ws + 1 * MB1;   // Wa_v^T
  u16* wt2 = ws + 2 * MB1;   // Wb_qk^T
  u16* wt3 = ws + 3 * MB1;   // Wb_v^T
  u16* wt4 = ws + 4 * MB1;   // Wa_o^T
  u16* wt5 = ws + 5 * MB1;   // Wb_o^T
  u16* aq  = ws + 6 * MB1;   // [B,L,E] bf16
  u16* bq  = ws + 10 * MB1;
  u16* av  = ws + 14 * MB1;
  u16* bv  = ws + 18 * MB1;
  u16* avT = ws + 22 * MB1;  // [B*H, D, L]
  u16* bvT = ws + 26 * MB1;  // [B*H, D, S]
  u16* bias_c = ws + 30 * MB1;            // 6*1024 bf16
  int* flag = (int*)(ws + 30 * MB1 + 8 * 1024);
  u16* a_ctx = av;  // alias: av consumed by transpose before attn writes
  u16* b_ctx = bv;

  dim3 blk(256);
  k_detect<<<1, 64, 0, stream>>>((const u16*)d_in[0], flag);
  k_cvt_bias<<<dim3(4, 6), blk, 0, stream>>>(d_in[3], d_in[5], d_in[7], d_in[9],
                                             d_in[11], d_in[13], bias_c, flag);
  k_transpose_w<<<dim3(16, 16, 6), blk, 0, stream>>>(
      d_in[2], d_in[4], d_in[6], d_in[8], d_in[10], d_in[12],
      wt0, wt1, wt2, wt3, wt4, wt5, flag);
  k_gemm_bias<<<dim3(8, 32), blk, 0, stream>>>(d_in[0], wt0, bias_c + 0 * 1024, aq,
                                               flag, 1, 0, 0, 4096, 1024, 1024);
  k_gemm_bias<<<dim3(8, 32), blk, 0, stream>>>(d_in[0], wt1, bias_c + 1 * 1024, av,
                                               flag, 1, 0, 0, 4096, 1024, 1024);
  k_gemm_bias<<<dim3(8, 32), blk, 0, stream>>>(d_in[1], wt2, bias_c + 2 * 1024, bq,
                                               flag, 1, 0, 0, 4096, 1024, 1024);
  k_gemm_bias<<<dim3(8, 32), blk, 0, stream>>>(d_in[1], wt3, bias_c + 3 * 1024, bv,
                                               flag, 1, 0, 0, 4096, 1024, 1024);
  k_transpose_v<<<dim3(32, 32), blk, 0, stream>>>(av, avT, 2048);
  k_transpose_v<<<dim3(32, 32), blk, 0, stream>>>(bv, bvT, 2048);
  k_attn<<<dim3(32, 32), blk, 0, stream>>>(aq, bq, bvT, a_ctx, 2048, 2048);
  k_attn<<<dim3(32, 32), blk, 0, stream>>>(bq, aq, avT, b_ctx, 2048, 2048);
  k_gemm_bias<<<dim3(8, 32), blk, 0, stream>>>(a_ctx, wt4, bias_c + 4 * 1024, d_out,
                                               flag, 0, 1, 0, 4096, 1024, 1024);
  k_gemm_bias<<<dim3(8, 32), blk, 0, stream>>>(b_ctx, wt5, bias_c + 5 * 1024, d_out,
                                               flag, 0, 1, 4 * MB1, 4096, 1024, 1024);
}

// Round 4
// 317.625 us; speedup vs baseline: 1.5335x; 1.5335x over previous
//
#include <hip/hip_runtime.h>
#include <hip/hip_bf16.h>
#include <stdint.h>

typedef unsigned short u16;
typedef __attribute__((ext_vector_type(8))) short bf16x8;
typedef __attribute__((ext_vector_type(4))) float f32x4;

typedef __attribute__((address_space(3))) void lds_void;
typedef const __attribute__((address_space(1))) void gbl_void;

#define SIDE 4194304u   // 4M elems = one side's [B,H,2048,64] / [4096,1024]
#define BHSTR 131072u   // 2048*64 per (b,h)

static __device__ __forceinline__ u16 f2bf(float f) {
  union { __hip_bfloat16 b; u16 u; } cv;
  cv.b = __float2bfloat16(f);
  return cv.u;
}
static __device__ __forceinline__ float bf2f(u16 u) {
  union { __hip_bfloat16 b; u16 u; } cv;
  cv.u = u;
  return __bfloat162float(cv.b);
}

// ---------------- input convert: a,b fp32 -> bf16 row-major ----------------
__global__ __launch_bounds__(256) void k_cvt_in(const float* __restrict__ a,
                                                const float* __restrict__ b,
                                                u16* __restrict__ dst) {
  int z = blockIdx.y;
  const float* src = z ? b : a;
  size_t i = ((size_t)blockIdx.x * 256 + threadIdx.x) * 8;
  float4 x0 = *(const float4*)(src + i);
  float4 x1 = *(const float4*)(src + i + 4);
  u16 t[8] = {f2bf(x0.x), f2bf(x0.y), f2bf(x0.z), f2bf(x0.w),
              f2bf(x1.x), f2bf(x1.y), f2bf(x1.z), f2bf(x1.w)};
  *(uint4*)(dst + (size_t)z * SIDE + i) = *(uint4*)t;
}

// ---------------- bias convert (fp32 -> bf16, concat, scale z0) -----------
__global__ __launch_bounds__(256) void k_cvt_bias(
    const float* s0, const float* s1, const float* s2, const float* s3,
    const float* s4, const float* s5, u16* __restrict__ dst) {
  const float* srcs[6] = {s0, s1, s2, s3, s4, s5};
  int z = blockIdx.y;
  int i = blockIdx.x * 256 + threadIdx.x;
  float sc = (z == 0) ? 0.125f : 1.0f;  // fold 1/sqrt(D) into ba_qk
  dst[z * 1024 + i] = f2bf(srcs[z][i] * sc);
}

// ---------------- weight transpose fp32 -> bf16, concat, scale z0 ---------
__global__ __launch_bounds__(256) void k_transpose_w(
    const float* a0, const float* a1, const float* a2, const float* a3,
    const float* a4, const float* a5,
    u16* d0, u16* d1, u16* d2, u16* d3, u16* d4, u16* d5) {
  __shared__ u16 tile[64][72];
  const float* srcs[6] = {a0, a1, a2, a3, a4, a5};
  u16* dsts[6] = {d0, d1, d2, d3, d4, d5};
  int z = blockIdx.z;
  float sc = (z == 0) ? 0.125f : 1.0f;  // fold 1/sqrt(D) into Wa_qk
  const float* src = srcs[z] + (size_t)(blockIdx.y * 64) * 1024 + blockIdx.x * 64;
  int t = threadIdx.x;
  int row = t >> 2, c4 = t & 3;
#pragma unroll
  for (int p = 0; p < 2; ++p) {
    int col = c4 * 8 + p * 32;
    const float* sf = src + (size_t)row * 1024 + col;
    float4 x0 = *(const float4*)sf;
    float4 x1 = *(const float4*)(sf + 4);
    u16 tmp[8] = {f2bf(x0.x * sc), f2bf(x0.y * sc), f2bf(x0.z * sc), f2bf(x0.w * sc),
                  f2bf(x1.x * sc), f2bf(x1.y * sc), f2bf(x1.z * sc), f2bf(x1.w * sc)};
    *(uint4*)(&tile[row][col]) = *(uint4*)tmp;
  }
  __syncthreads();
  u16* dst = dsts[z] + (size_t)(blockIdx.x * 64) * 1024 + blockIdx.y * 64;
#pragma unroll
  for (int p = 0; p < 2; ++p) {
    int col = c4 * 8 + p * 32;
    u16 tmp[8];
#pragma unroll
    for (int i = 0; i < 8; ++i) tmp[i] = tile[col + i][row];
    *(uint4*)(dst + (size_t)row * 1024 + col) = *(uint4*)tmp;
  }
}

// ---------------- QKV projection: [4096,1024]bf16 @ WtAB[2048,1024]^T -----
// n<1024 -> qk packed [b,h,n,64]; n>=1024 -> v packed [b,h,n,64].
__global__ __launch_bounds__(256) void k_gemm_qkv(
    const u16* __restrict__ Aall, const u16* __restrict__ WtA,
    const u16* __restrict__ WtB, const u16* __restrict__ bias,
    u16* __restrict__ qkbuf, u16* __restrict__ vbuf) {
  __shared__ u16 As[128 * 32];
  __shared__ u16 Bs[128 * 32];
  int tid = threadIdx.x;
  int wave = tid >> 6, lane = tid & 63;
  int quad = lane >> 4, lrow = lane & 15;
  int wr = wave >> 1, wc = wave & 1;
  int z = blockIdx.z;
  int m0 = blockIdx.y * 128, n0 = blockIdx.x * 128;
  const u16* A = Aall + (size_t)z * SIDE;
  const u16* Wt = z ? WtB : WtA;
  const u16* bi = bias + (size_t)z * 2048;

  f32x4 acc[4][4] = {};
  int srow = 32 * wave + (lane >> 2);
  int scol = (lane & 3) * 8;
  const u16* gA = A + (size_t)(m0 + srow) * 1024 + scol;
  const u16* gB = Wt + (size_t)(n0 + srow) * 1024 + scol;
  u16* lA = &As[(32 * wave) * 32];
  u16* lB = &Bs[(32 * wave) * 32];

  for (int k0 = 0; k0 < 1024; k0 += 32) {
    __syncthreads();
#pragma unroll
    for (int j = 0; j < 2; ++j) {
      __builtin_amdgcn_global_load_lds((gbl_void*)(gA + (size_t)(16 * j) * 1024 + k0),
                                       (lds_void*)(lA + 16 * j * 32), 16, 0, 0);
      __builtin_amdgcn_global_load_lds((gbl_void*)(gB + (size_t)(16 * j) * 1024 + k0),
                                       (lds_void*)(lB + 16 * j * 32), 16, 0, 0);
    }
    __syncthreads();
    bf16x8 af[4], bfr[4];
#pragma unroll
    for (int i = 0; i < 4; ++i)
      af[i] = *(const bf16x8*)&As[(64 * wr + 16 * i + lrow) * 32 + 8 * quad];
#pragma unroll
    for (int j = 0; j < 4; ++j)
      bfr[j] = *(const bf16x8*)&Bs[(64 * wc + 16 * j + lrow) * 32 + 8 * quad];
#pragma unroll
    for (int i = 0; i < 4; ++i)
#pragma unroll
      for (int j = 0; j < 4; ++j)
        acc[i][j] = __builtin_amdgcn_mfma_f32_16x16x32_bf16(af[i], bfr[j], acc[i][j], 0, 0, 0);
  }

  int x = blockIdx.x;
  bool isv = (x >= 8);
  int h = (isv ? 2 * (x - 8) : 2 * x) + wc;  // head this wave writes
  u16* dst = (isv ? vbuf : qkbuf) + (size_t)z * SIDE;

  float bv[4];
#pragma unroll
  for (int j = 0; j < 4; ++j) bv[j] = bf2f(bi[n0 + 64 * wc + 16 * j + lrow]);

#pragma unroll
  for (int i = 0; i < 4; ++i) {
    int row0 = m0 + 64 * wr + 16 * i + 4 * quad;
#pragma unroll
    for (int r = 0; r < 4; ++r) {
      int rg = row0 + r;
      int bb = rg >> 11, rl = rg & 2047;
      u16* dr = dst + (size_t)(bb * 16 + h) * BHSTR + (size_t)rl * 64;
#pragma unroll
      for (int j = 0; j < 4; ++j)
        dr[16 * j + lrow] = f2bf(acc[i][j][r] + bv[j]);
    }
  }
}

// ---------------- V transpose per head: [sbh][2048][64] -> [sbh][64][2048] --
__global__ __launch_bounds__(256) void k_transpose_v(const u16* __restrict__ v,
                                                     u16* __restrict__ vt) {
  __shared__ u16 tile[64][72];
  int sbh = blockIdx.y;
  int n0 = blockIdx.x * 64;
  const u16* src = v + (size_t)sbh * BHSTR + (size_t)n0 * 64;
  u16* dst = vt + (size_t)sbh * BHSTR + n0;
  int t = threadIdx.x;
  int row = t >> 2, c4 = t & 3;
#pragma unroll
  for (int p = 0; p < 2; ++p) {
    int col = c4 * 8 + p * 32;
    uint4 q = *(const uint4*)(src + (size_t)row * 64 + col);
    *(uint4*)(&tile[row][col]) = q;
  }
  __syncthreads();
#pragma unroll
  for (int p = 0; p < 2; ++p) {
    int col = c4 * 8 + p * 32;
    u16 tmp[8];
#pragma unroll
    for (int i = 0; i < 8; ++i) tmp[i] = tile[col + i][row];
    *(uint4*)(dst + (size_t)row * 2048 + col) = *(uint4*)tmp;
  }
}

// ---------------- fused dual-softmax attention, both sides ----------------
// z=0: Q=aq,K=bq,V=bv -> a_ctx ; z=1: Q=bq,K=aq,V=av -> b_ctx
// 128 Q-rows/block, 32/wave. Q/K/V DMA-staged with XOR-granule swizzle.
__global__ __launch_bounds__(256) void k_attn(
    const u16* __restrict__ qk, const u16* __restrict__ vt,
    u16* __restrict__ ctx) {
  __shared__ u16 Ks[64 * 64];
  __shared__ u16 Vs[64 * 64];
  __shared__ u16 Ps[128 * 72];  // also Q staging area (16KB of 18KB)
  int tid = threadIdx.x;
  int wave = tid >> 6, lane = tid & 63;
  int quad = lane >> 4, lrow = lane & 15;
  int z = blockIdx.z, bh = blockIdx.y;
  int l0 = blockIdx.x * 128;
  const u16* Qb = qk + (size_t)z * SIDE + (size_t)bh * BHSTR + (size_t)l0 * 64;
  const u16* Kb = qk + (size_t)(1 - z) * SIDE + (size_t)bh * BHSTR;
  const u16* Vtb = vt + (size_t)(1 - z) * SIDE + (size_t)bh * BHSTR;

  // stage Q swizzled into Ps region
#pragma unroll
  for (int p = 0; p < 4; ++p) {
    int G0 = wave * 256 + p * 64;
    int G = G0 + lane;
    int row = G >> 3, c = G & 7;
    const u16* src = Qb + (size_t)row * 64 + ((c ^ (row & 7)) * 8);
    __builtin_amdgcn_global_load_lds((gbl_void*)src, (lds_void*)(Ps + G0 * 8), 16, 0, 0);
  }
  __syncthreads();
  bf16x8 qf[2][2];
#pragma unroll
  for (int rt = 0; rt < 2; ++rt) {
    int lq = 32 * wave + 16 * rt + lrow;
    qf[rt][0] = *(const bf16x8*)&Ps[(lq * 8 + (quad ^ (lq & 7))) * 8];
    qf[rt][1] = *(const bf16x8*)&Ps[(lq * 8 + ((quad + 4) ^ (lq & 7))) * 8];
  }

  f32x4 cacc[2][4] = {};
  float rsum[2][4] = {};

  for (int s0 = 0; s0 < 2048; s0 += 64) {
    __syncthreads();  // protect prev-iter K/V reads (and iter0 Q reads)
#pragma unroll
    for (int p = 0; p < 2; ++p) {
      int G0 = p * 256 + wave * 64;
      int G = G0 + lane;
      int row = G >> 3, c = G & 7;
      int sw = (c ^ (row & 7)) * 8;
      __builtin_amdgcn_global_load_lds((gbl_void*)(Kb + (size_t)(s0 + row) * 64 + sw),
                                       (lds_void*)(Ks + G0 * 8), 16, 0, 0);
      __builtin_amdgcn_global_load_lds((gbl_void*)(Vtb + (size_t)row * 2048 + s0 + sw),
                                       (lds_void*)(Vs + G0 * 8), 16, 0, 0);
    }
    __syncthreads();
    // QK^T (scale pre-folded into aq) + exp -> Ps rows 32w..32w+31
#pragma unroll
    for (int j = 0; j < 4; ++j) {
      int kr = 16 * j + lrow;
      bf16x8 kf0 = *(const bf16x8*)&Ks[(kr * 8 + (quad ^ (kr & 7))) * 8];
      bf16x8 kf1 = *(const bf16x8*)&Ks[(kr * 8 + ((quad + 4) ^ (kr & 7))) * 8];
#pragma unroll
      for (int rt = 0; rt < 2; ++rt) {
        f32x4 s = {};
        s = __builtin_amdgcn_mfma_f32_16x16x32_bf16(qf[rt][0], kf0, s, 0, 0, 0);
        s = __builtin_amdgcn_mfma_f32_16x16x32_bf16(qf[rt][1], kf1, s, 0, 0, 0);
        u16* pp = &Ps[(32 * wave + 16 * rt + 4 * quad) * 72 + lrow];
#pragma unroll
        for (int r = 0; r < 4; ++r) {
          float pv = __expf(s[r]);
          rsum[rt][r] += pv;
          pp[r * 72 + 16 * j] = f2bf(pv);
        }
      }
    }
    // wave-private Ps round-trip: drain DS writes, forbid reordering
    asm volatile("s_waitcnt lgkmcnt(0)" ::: "memory");
    bf16x8 pf[2][2];
#pragma unroll
    for (int rt = 0; rt < 2; ++rt) {
      const u16* q = &Ps[(32 * wave + 16 * rt + lrow) * 72];
      pf[rt][0] = *(const bf16x8*)(q + 8 * quad);
      pf[rt][1] = *(const bf16x8*)(q + 32 + 8 * quad);
    }
    // P @ V
#pragma unroll
    for (int j = 0; j < 4; ++j) {
      int vr = 16 * j + lrow;
      bf16x8 vf0 = *(const bf16x8*)&Vs[(vr * 8 + (quad ^ (vr & 7))) * 8];
      bf16x8 vf1 = *(const bf16x8*)&Vs[(vr * 8 + ((quad + 4) ^ (vr & 7))) * 8];
#pragma unroll
      for (int rt = 0; rt < 2; ++rt) {
        cacc[rt][j] = __builtin_amdgcn_mfma_f32_16x16x32_bf16(pf[rt][0], vf0, cacc[rt][j], 0, 0, 0);
        cacc[rt][j] = __builtin_amdgcn_mfma_f32_16x16x32_bf16(pf[rt][1], vf1, cacc[rt][j], 0, 0, 0);
      }
    }
  }

  float rinv[2][4];
#pragma unroll
  for (int rt = 0; rt < 2; ++rt)
#pragma unroll
    for (int r = 0; r < 4; ++r) {
      float v = rsum[rt][r];
      v += __shfl_xor(v, 1);
      v += __shfl_xor(v, 2);
      v += __shfl_xor(v, 4);
      v += __shfl_xor(v, 8);
      rinv[rt][r] = 1.0f / v;
    }

  int bb = bh >> 4, h = bh & 15;
  u16* Ob = ctx + (size_t)z * SIDE + (size_t)(bb * 2048 + l0) * 1024 + h * 64;
#pragma unroll
  for (int rt = 0; rt < 2; ++rt)
#pragma unroll
    for (int r = 0; r < 4; ++r) {
      int l = 32 * wave + 16 * rt + 4 * quad + r;
#pragma unroll
      for (int j = 0; j < 4; ++j)
        Ob[(size_t)l * 1024 + 16 * j + lrow] = f2bf(cacc[rt][j][r] * rinv[rt][r]);
    }
}

// ---------------- O projection: ctx[4096,1024]bf16 @ WtO^T + bias -> fp32 --
__global__ __launch_bounds__(256) void k_gemm_o(
    const u16* __restrict__ ctx, const u16* __restrict__ WtO,
    const u16* __restrict__ bias, float* __restrict__ out) {
  __shared__ u16 As[128 * 32];
  __shared__ u16 Bs[128 * 32];
  int tid = threadIdx.x;
  int wave = tid >> 6, lane = tid & 63;
  int quad = lane >> 4, lrow = lane & 15;
  int wr = wave >> 1, wc = wave & 1;
  int z = blockIdx.z;
  int m0 = blockIdx.y * 128, n0 = blockIdx.x * 128;
  const u16* A = ctx + (size_t)z * SIDE;
  const u16* Wt = WtO + (size_t)z * 1048576;
  const u16* bi = bias + (size_t)z * 1024;
  float* C = out + (size_t)z * SIDE;

  f32x4 acc[4][4] = {};
  int srow = 32 * wave + (lane >> 2);
  int scol = (lane & 3) * 8;
  const u16* gA = A + (size_t)(m0 + srow) * 1024 + scol;
  const u16* gB = Wt + (size_t)(n0 + srow) * 1024 + scol;
  u16* lA = &As[(32 * wave) * 32];
  u16* lB = &Bs[(32 * wave) * 32];

  for (int k0 = 0; k0 < 1024; k0 += 32) {
    __syncthreads();
#pragma unroll
    for (int j = 0; j < 2; ++j) {
      __builtin_amdgcn_global_load_lds((gbl_void*)(gA + (size_t)(16 * j) * 1024 + k0),
                                       (lds_void*)(lA + 16 * j * 32), 16, 0, 0);
      __builtin_amdgcn_global_load_lds((gbl_void*)(gB + (size_t)(16 * j) * 1024 + k0),
                                       (lds_void*)(lB + 16 * j * 32), 16, 0, 0);
    }
    __syncthreads();
    bf16x8 af[4], bfr[4];
#pragma unroll
    for (int i = 0; i < 4; ++i)
      af[i] = *(const bf16x8*)&As[(64 * wr + 16 * i + lrow) * 32 + 8 * quad];
#pragma unroll
    for (int j = 0; j < 4; ++j)
      bfr[j] = *(const bf16x8*)&Bs[(64 * wc + 16 * j + lrow) * 32 + 8 * quad];
#pragma unroll
    for (int i = 0; i < 4; ++i)
#pragma unroll
      for (int j = 0; j < 4; ++j)
        acc[i][j] = __builtin_amdgcn_mfma_f32_16x16x32_bf16(af[i], bfr[j], acc[i][j], 0, 0, 0);
  }

  float bv[4];
#pragma unroll
  for (int j = 0; j < 4; ++j) bv[j] = bf2f(bi[n0 + 64 * wc + 16 * j + lrow]);
#pragma unroll
  for (int i = 0; i < 4; ++i) {
    int row = m0 + 64 * wr + 16 * i + 4 * quad;
#pragma unroll
    for (int j = 0; j < 4; ++j) {
      int col = n0 + 64 * wc + 16 * j + lrow;
#pragma unroll
      for (int r = 0; r < 4; ++r)
        C[(size_t)(row + r) * 1024 + col] = acc[i][j][r] + bv[j];
    }
  }
}

extern "C" void kernel_launch(void* const* d_in, const int* in_sizes, int n_in,
                              void* d_out, int out_size, void* d_ws, size_t ws_size,
                              hipStream_t stream) {
  (void)in_sizes; (void)n_in; (void)out_size; (void)ws_size;
  const size_t M1 = 1048576u;
  u16* ws = (u16*)d_ws;
  u16* wtA   = ws;             // [2048,1024] concat(Wa_qk^T*0.125, Wa_v^T)
  u16* wtB   = ws + 2 * M1;    // [2048,1024] concat(Wb_qk^T, Wb_v^T)
  u16* wtO   = ws + 4 * M1;    // [2048,1024] concat(Wa_o^T, Wb_o^T)
  u16* biasQ = ws + 6 * M1;    // [2,2048] concat per side
  u16* biasO = ws + 6 * M1 + 4096;  // [2,1024]
  u16* ab    = ws + 7 * M1;    // [2][4096,1024] bf16 inputs (dead after QKV)
  u16* vt    = ab;             // alias: [2][bh][64][2048]
  u16* qkbuf = ws + 15 * M1;   // [2][bh][2048][64]
  u16* vbuf  = ws + 23 * M1;   // [2][bh][2048][64] (dead after transpose_v)
  u16* ctx   = vbuf;           // alias: [2][4096,1024]

  dim3 blk(256);
  k_cvt_in<<<dim3(2048, 2), blk, 0, stream>>>((const float*)d_in[0],
                                              (const float*)d_in[1], ab);
  // bias concat order: [ba_qk|ba_v] [bb_qk|bb_v] [ba_o|bb_o]
  k_cvt_bias<<<dim3(4, 6), blk, 0, stream>>>(
      (const float*)d_in[3], (const float*)d_in[5], (const float*)d_in[7],
      (const float*)d_in[9], (const float*)d_in[11], (const float*)d_in[13], biasQ);
  k_transpose_w<<<dim3(16, 16, 6), blk, 0, stream>>>(
      (const float*)d_in[2], (const float*)d_in[4], (const float*)d_in[6],
      (const float*)d_in[8], (const float*)d_in[10], (const float*)d_in[12],
      wtA, wtA + M1, wtB, wtB + M1, wtO, wtO + M1);
  k_gemm_qkv<<<dim3(16, 32, 2), blk, 0, stream>>>(ab, wtA, wtB, biasQ, qkbuf, vbuf);
  k_transpose_v<<<dim3(32, 64), blk, 0, stream>>>(vbuf, vt);
  k_attn<<<dim3(16, 32, 2), blk, 0, stream>>>(qkbuf, vt, ctx);
  k_gemm_o<<<dim3(8, 32, 2), blk, 0, stream>>>(ctx, wtO, biasO, (float*)d_out);
}

// Round 5
// 315.136 us; speedup vs baseline: 1.5456x; 1.0079x over previous
//
#include <hip/hip_runtime.h>
#include <hip/hip_bf16.h>
#include <stdint.h>

typedef unsigned short u16;
typedef unsigned int u32;
typedef __attribute__((ext_vector_type(8))) short bf16x8;
typedef __attribute__((ext_vector_type(4))) float f32x4;

typedef __attribute__((address_space(3))) void lds_void;
typedef const __attribute__((address_space(1))) void gbl_void;

#define SIDE 4194304u   // 4M elems = one side's [B,H,2048,64] / [4096,1024]
#define BHSTR 131072u   // 2048*64 per (b,h)

static __device__ __forceinline__ u16 f2bf(float f) {
  union { __hip_bfloat16 b; u16 u; } cv;
  cv.b = __float2bfloat16(f);
  return cv.u;
}
static __device__ __forceinline__ float bf2f(u16 u) {
  union { __hip_bfloat16 b; u16 u; } cv;
  cv.u = u;
  return __bfloat162float(cv.b);
}

// ---------------- input convert: a,b fp32 -> bf16 row-major ----------------
__global__ __launch_bounds__(256) void k_cvt_in(const float* __restrict__ a,
                                                const float* __restrict__ b,
                                                u16* __restrict__ dst) {
  int z = blockIdx.y;
  const float* src = z ? b : a;
  size_t i = ((size_t)blockIdx.x * 256 + threadIdx.x) * 8;
  float4 x0 = *(const float4*)(src + i);
  float4 x1 = *(const float4*)(src + i + 4);
  u16 t[8] = {f2bf(x0.x), f2bf(x0.y), f2bf(x0.z), f2bf(x0.w),
              f2bf(x1.x), f2bf(x1.y), f2bf(x1.z), f2bf(x1.w)};
  *(uint4*)(dst + (size_t)z * SIDE + i) = *(uint4*)t;
}

// ---------------- bias convert (fp32 -> bf16, concat, scale z0) -----------
__global__ __launch_bounds__(256) void k_cvt_bias(
    const float* s0, const float* s1, const float* s2, const float* s3,
    const float* s4, const float* s5, u16* __restrict__ dst) {
  const float* srcs[6] = {s0, s1, s2, s3, s4, s5};
  int z = blockIdx.y;
  int i = blockIdx.x * 256 + threadIdx.x;
  float sc = (z == 0) ? 0.125f : 1.0f;  // fold 1/sqrt(D) into ba_qk
  dst[z * 1024 + i] = f2bf(srcs[z][i] * sc);
}

// ---------------- weight transpose fp32 -> bf16, concat, scale z0 ---------
__global__ __launch_bounds__(256) void k_transpose_w(
    const float* a0, const float* a1, const float* a2, const float* a3,
    const float* a4, const float* a5,
    u16* d0, u16* d1, u16* d2, u16* d3, u16* d4, u16* d5) {
  __shared__ u16 tile[64][72];
  const float* srcs[6] = {a0, a1, a2, a3, a4, a5};
  u16* dsts[6] = {d0, d1, d2, d3, d4, d5};
  int z = blockIdx.z;
  float sc = (z == 0) ? 0.125f : 1.0f;  // fold 1/sqrt(D) into Wa_qk
  const float* src = srcs[z] + (size_t)(blockIdx.y * 64) * 1024 + blockIdx.x * 64;
  int t = threadIdx.x;
  int row = t >> 2, c4 = t & 3;
#pragma unroll
  for (int p = 0; p < 2; ++p) {
    int col = c4 * 8 + p * 32;
    const float* sf = src + (size_t)row * 1024 + col;
    float4 x0 = *(const float4*)sf;
    float4 x1 = *(const float4*)(sf + 4);
    u16 tmp[8] = {f2bf(x0.x * sc), f2bf(x0.y * sc), f2bf(x0.z * sc), f2bf(x0.w * sc),
                  f2bf(x1.x * sc), f2bf(x1.y * sc), f2bf(x1.z * sc), f2bf(x1.w * sc)};
    *(uint4*)(&tile[row][col]) = *(uint4*)tmp;
  }
  __syncthreads();
  u16* dst = dsts[z] + (size_t)(blockIdx.x * 64) * 1024 + blockIdx.y * 64;
#pragma unroll
  for (int p = 0; p < 2; ++p) {
    int col = c4 * 8 + p * 32;
    u16 tmp[8];
#pragma unroll
    for (int i = 0; i < 8; ++i) tmp[i] = tile[col + i][row];
    *(uint4*)(dst + (size_t)row * 1024 + col) = *(uint4*)tmp;
  }
}

// ---------------- QKV projection: [4096,1024]bf16 @ WtAB[2048,1024]^T -----
// n<1024 -> qk packed [b,h,n,64]; n>=1024 -> v packed [b,h,n,64].
// Epilogue transposes through LDS for coalesced b128 stores.
__global__ __launch_bounds__(256) void k_gemm_qkv(
    const u16* __restrict__ Aall, const u16* __restrict__ WtA,
    const u16* __restrict__ WtB, const u16* __restrict__ bias,
    u16* __restrict__ qkbuf, u16* __restrict__ vbuf) {
  __shared__ u16 Sh[8192];
  u16* As = Sh;
  u16* Bs = Sh + 4096;
  int tid = threadIdx.x;
  int wave = tid >> 6, lane = tid & 63;
  int quad = lane >> 4, lrow = lane & 15;
  int wr = wave >> 1, wc = wave & 1;
  int z = blockIdx.z;
  int m0 = blockIdx.y * 128, n0 = blockIdx.x * 128;
  const u16* A = Aall + (size_t)z * SIDE;
  const u16* Wt = z ? WtB : WtA;
  const u16* bi = bias + (size_t)z * 2048;

  f32x4 acc[4][4] = {};
  int srow = 32 * wave + (lane >> 2);
  int scol = (lane & 3) * 8;
  const u16* gA = A + (size_t)(m0 + srow) * 1024 + scol;
  const u16* gB = Wt + (size_t)(n0 + srow) * 1024 + scol;
  u16* lA = &As[(32 * wave) * 32];
  u16* lB = &Bs[(32 * wave) * 32];

  for (int k0 = 0; k0 < 1024; k0 += 32) {
    __syncthreads();
#pragma unroll
    for (int j = 0; j < 2; ++j) {
      __builtin_amdgcn_global_load_lds((gbl_void*)(gA + (size_t)(16 * j) * 1024 + k0),
                                       (lds_void*)(lA + 16 * j * 32), 16, 0, 0);
      __builtin_amdgcn_global_load_lds((gbl_void*)(gB + (size_t)(16 * j) * 1024 + k0),
                                       (lds_void*)(lB + 16 * j * 32), 16, 0, 0);
    }
    __syncthreads();
    bf16x8 af[4], bfr[4];
#pragma unroll
    for (int i = 0; i < 4; ++i)
      af[i] = *(const bf16x8*)&As[(64 * wr + 16 * i + lrow) * 32 + 8 * quad];
#pragma unroll
    for (int j = 0; j < 4; ++j)
      bfr[j] = *(const bf16x8*)&Bs[(64 * wc + 16 * j + lrow) * 32 + 8 * quad];
#pragma unroll
    for (int i = 0; i < 4; ++i)
#pragma unroll
      for (int j = 0; j < 4; ++j)
        acc[i][j] = __builtin_amdgcn_mfma_f32_16x16x32_bf16(af[i], bfr[j], acc[i][j], 0, 0, 0);
  }

  float bv[4];
#pragma unroll
  for (int j = 0; j < 4; ++j) bv[j] = bf2f(bi[n0 + 64 * wc + 16 * j + lrow]);

  int x = blockIdx.x;
  bool isv = (x >= 8);
  int h = (isv ? 2 * (x - 8) : 2 * x) + wc;
  u16* dst = (isv ? vbuf : qkbuf) + (size_t)z * SIDE;
  u16* lw = Sh + wave * 1216;  // 16 rows * stride 76 per wave

  __syncthreads();  // all waves done reading As/Bs
#pragma unroll
  for (int i = 0; i < 4; ++i) {
#pragma unroll
    for (int j = 0; j < 4; ++j)
#pragma unroll
      for (int r = 0; r < 4; ++r)
        lw[(4 * quad + r) * 76 + 16 * j + lrow] = f2bf(acc[i][j][r] + bv[j]);
    asm volatile("s_waitcnt lgkmcnt(0)" ::: "memory");
    int row = lane >> 2, cg = (lane & 3) * 16;
    int rg = m0 + 64 * wr + 16 * i + row;
    int bb = rg >> 11, rl = rg & 2047;
    u16* dr = dst + (size_t)(bb * 16 + h) * BHSTR + (size_t)rl * 64 + cg;
    uint2 w0 = *(const uint2*)&lw[row * 76 + cg];
    uint2 w1 = *(const uint2*)&lw[row * 76 + cg + 4];
    uint2 w2 = *(const uint2*)&lw[row * 76 + cg + 8];
    uint2 w3 = *(const uint2*)&lw[row * 76 + cg + 12];
    uint4 o0 = {w0.x, w0.y, w1.x, w1.y};
    uint4 o1 = {w2.x, w2.y, w3.x, w3.y};
    *(uint4*)dr = o0;
    *(uint4*)(dr + 8) = o1;
    asm volatile("s_waitcnt lgkmcnt(0)" ::: "memory");  // WAR fence before next pass
  }
}

// ---------------- V transpose per head: [sbh][2048][64] -> [sbh][64][2048] --
__global__ __launch_bounds__(256) void k_transpose_v(const u16* __restrict__ v,
                                                     u16* __restrict__ vt) {
  __shared__ u16 tile[64][72];
  int sbh = blockIdx.y;
  int n0 = blockIdx.x * 64;
  const u16* src = v + (size_t)sbh * BHSTR + (size_t)n0 * 64;
  u16* dst = vt + (size_t)sbh * BHSTR + n0;
  int t = threadIdx.x;
  int row = t >> 2, c4 = t & 3;
#pragma unroll
  for (int p = 0; p < 2; ++p) {
    int col = c4 * 8 + p * 32;
    uint4 q = *(const uint4*)(src + (size_t)row * 64 + col);
    *(uint4*)(&tile[row][col]) = q;
  }
  __syncthreads();
#pragma unroll
  for (int p = 0; p < 2; ++p) {
    int col = c4 * 8 + p * 32;
    u16 tmp[8];
#pragma unroll
    for (int i = 0; i < 8; ++i) tmp[i] = tile[col + i][row];
    *(uint4*)(dst + (size_t)row * 2048 + col) = *(uint4*)tmp;
  }
}

// ---------------- fused dual-softmax attention, both sides ----------------
// z=0: Q=aq,K=bq,V=bv -> a_ctx ; z=1: Q=bq,K=aq,V=av -> b_ctx
// S^T via A=K,B=Q; Ps packed b64 writes, swizzled, b128 A-frag reads.
// Double-buffered K/V prefetch: one barrier per 64-s round.
__global__ __launch_bounds__(256) void k_attn(
    const u16* __restrict__ qk, const u16* __restrict__ vt,
    u16* __restrict__ ctx) {
  __shared__ u16 Ks[2 * 4096];
  __shared__ u16 Vs[2 * 4096];
  __shared__ u16 Ps[128 * 64];  // Q staging, then P tiles (wave-private rows)
  int tid = threadIdx.x;
  int wave = tid >> 6, lane = tid & 63;
  int quad = lane >> 4, lrow = lane & 15;
  int z = blockIdx.z, bh = blockIdx.x;      // x=bh: l-tiles of one (z,bh) share an XCD
  int l0 = blockIdx.y * 128;
  const u16* Qb = qk + (size_t)z * SIDE + (size_t)bh * BHSTR + (size_t)l0 * 64;
  const u16* Kb = qk + (size_t)(1 - z) * SIDE + (size_t)bh * BHSTR;
  const u16* Vtb = vt + (size_t)(1 - z) * SIDE + (size_t)bh * BHSTR;

  // stage Q (granule-swizzled); wave w stages exactly its own rows 32w..32w+31
#pragma unroll
  for (int p = 0; p < 4; ++p) {
    int G0 = wave * 256 + p * 64;
    int G = G0 + lane;
    int row = G >> 3, c = G & 7;
    __builtin_amdgcn_global_load_lds((gbl_void*)(Qb + (size_t)row * 64 + ((c ^ (row & 7)) * 8)),
                                     (lds_void*)(Ps + G0 * 8), 16, 0, 0);
  }
  // stage K/V round 0 into buffer 0
#pragma unroll
  for (int p = 0; p < 2; ++p) {
    int G0 = p * 256 + wave * 64;
    int G = G0 + lane;
    int row = G >> 3, c = G & 7;
    int sw = (c ^ (row & 7)) * 8;
    __builtin_amdgcn_global_load_lds((gbl_void*)(Kb + (size_t)row * 64 + sw),
                                     (lds_void*)(Ks + G0 * 8), 16, 0, 0);
    __builtin_amdgcn_global_load_lds((gbl_void*)(Vtb + (size_t)row * 2048 + sw),
                                     (lds_void*)(Vs + G0 * 8), 16, 0, 0);
  }

  bf16x8 qf[2][2];
  f32x4 cacc[2][4] = {};
  float rsum[2] = {0.f, 0.f};
  int e = 2 * (lrow & 7);

  for (int it = 0; it < 32; ++it) {
    __syncthreads();  // vmcnt(0)+barrier: prev-issued DMAs (overlapped) now visible
    if (it == 0) {
#pragma unroll
      for (int rt = 0; rt < 2; ++rt) {
        int lq = 32 * wave + 16 * rt + lrow;
        qf[rt][0] = *(const bf16x8*)&Ps[(lq * 8 + (quad ^ (lq & 7))) * 8];
        qf[rt][1] = *(const bf16x8*)&Ps[(lq * 8 + ((quad + 4) ^ (lq & 7))) * 8];
      }
    }
    int prty = it & 1;
    if (it + 1 < 32) {  // prefetch next round into other buffer
      int s1 = (it + 1) << 6;
      int nb = (1 - prty) * 4096;
#pragma unroll
      for (int p = 0; p < 2; ++p) {
        int G0 = p * 256 + wave * 64;
        int G = G0 + lane;
        int row = G >> 3, c = G & 7;
        int sw = (c ^ (row & 7)) * 8;
        __builtin_amdgcn_global_load_lds((gbl_void*)(Kb + (size_t)(s1 + row) * 64 + sw),
                                         (lds_void*)(Ks + nb + G0 * 8), 16, 0, 0);
        __builtin_amdgcn_global_load_lds((gbl_void*)(Vtb + (size_t)row * 2048 + s1 + sw),
                                         (lds_void*)(Vs + nb + G0 * 8), 16, 0, 0);
      }
    }
    const u16* KsC = Ks + prty * 4096;
    const u16* VsC = Vs + prty * 4096;
    // S^T = K·Q^T (scale pre-folded), exp, packed b64 -> Ps (l-major, swizzled)
#pragma unroll
    for (int j = 0; j < 4; ++j) {
      int kr = 16 * j + lrow;
      bf16x8 kf0 = *(const bf16x8*)&KsC[(kr * 8 + (quad ^ (kr & 7))) * 8];
      bf16x8 kf1 = *(const bf16x8*)&KsC[(kr * 8 + ((quad + 4) ^ (kr & 7))) * 8];
#pragma unroll
      for (int rt = 0; rt < 2; ++rt) {
        f32x4 s = {};
        s = __builtin_amdgcn_mfma_f32_16x16x32_bf16(kf0, qf[rt][0], s, 0, 0, 0);
        s = __builtin_amdgcn_mfma_f32_16x16x32_bf16(kf1, qf[rt][1], s, 0, 0, 0);
        float e0 = __expf(s[0]), e1 = __expf(s[1]);
        float e2 = __expf(s[2]), e3 = __expf(s[3]);
        rsum[rt] += (e0 + e1) + (e2 + e3);
        uint2 pk;
        pk.x = ((u32)f2bf(e1) << 16) | (u32)f2bf(e0);
        pk.y = ((u32)f2bf(e3) << 16) | (u32)f2bf(e2);
        *(uint2*)&Ps[(32 * wave + 16 * rt + lrow) * 64 + ((4 * j + quad) ^ e) * 4] = pk;
      }
    }
    asm volatile("s_waitcnt lgkmcnt(0)" ::: "memory");  // wave-private Ps round-trip
    bf16x8 pf[2][2];
#pragma unroll
    for (int rt = 0; rt < 2; ++rt) {
      const u16* pr = &Ps[(32 * wave + 16 * rt + lrow) * 64];
      pf[rt][0] = *(const bf16x8*)&pr[((2 * quad) ^ e) * 4];
      pf[rt][1] = *(const bf16x8*)&pr[((2 * quad + 8) ^ e) * 4];
    }
    // P @ V
#pragma unroll
    for (int j = 0; j < 4; ++j) {
      int vr = 16 * j + lrow;
      bf16x8 vf0 = *(const bf16x8*)&VsC[(vr * 8 + (quad ^ (vr & 7))) * 8];
      bf16x8 vf1 = *(const bf16x8*)&VsC[(vr * 8 + ((quad + 4) ^ (vr & 7))) * 8];
#pragma unroll
      for (int rt = 0; rt < 2; ++rt) {
        cacc[rt][j] = __builtin_amdgcn_mfma_f32_16x16x32_bf16(pf[rt][0], vf0, cacc[rt][j], 0, 0, 0);
        cacc[rt][j] = __builtin_amdgcn_mfma_f32_16x16x32_bf16(pf[rt][1], vf1, cacc[rt][j], 0, 0, 0);
      }
    }
  }

  float rinv[2][4];
#pragma unroll
  for (int rt = 0; rt < 2; ++rt) {
    float v = rsum[rt];
    v += __shfl_xor(v, 16);
    v += __shfl_xor(v, 32);
    float rv = 1.0f / v;
#pragma unroll
    for (int r = 0; r < 4; ++r)
      rinv[rt][r] = __shfl(rv, 20 * quad + r);  // total for l_local = 4*quad + r
  }

  int bb = bh >> 4, h = bh & 15;
  u16* Ob = ctx + (size_t)z * SIDE + (size_t)(bb * 2048 + l0) * 1024 + h * 64;
#pragma unroll
  for (int rt = 0; rt < 2; ++rt)
#pragma unroll
    for (int r = 0; r < 4; ++r) {
      int l = 32 * wave + 16 * rt + 4 * quad + r;
#pragma unroll
      for (int j = 0; j < 4; ++j)
        Ob[(size_t)l * 1024 + 16 * j + lrow] = f2bf(cacc[rt][j][r] * rinv[rt][r]);
    }
}

// ---------------- O projection: ctx[4096,1024]bf16 @ WtO^T + bias -> fp32 --
__global__ __launch_bounds__(256) void k_gemm_o(
    const u16* __restrict__ ctx, const u16* __restrict__ WtO,
    const u16* __restrict__ bias, float* __restrict__ out) {
  __shared__ u16 As[128 * 32];
  __shared__ u16 Bs[128 * 32];
  int tid = threadIdx.x;
  int wave = tid >> 6, lane = tid & 63;
  int quad = lane >> 4, lrow = lane & 15;
  int wr = wave >> 1, wc = wave & 1;
  int z = blockIdx.z;
  int m0 = blockIdx.y * 128, n0 = blockIdx.x * 128;
  const u16* A = ctx + (size_t)z * SIDE;
  const u16* Wt = WtO + (size_t)z * 1048576;
  const u16* bi = bias + (size_t)z * 1024;
  float* C = out + (size_t)z * SIDE;

  f32x4 acc[4][4] = {};
  int srow = 32 * wave + (lane >> 2);
  int scol = (lane & 3) * 8;
  const u16* gA = A + (size_t)(m0 + srow) * 1024 + scol;
  const u16* gB = Wt + (size_t)(n0 + srow) * 1024 + scol;
  u16* lA = &As[(32 * wave) * 32];
  u16* lB = &Bs[(32 * wave) * 32];

  for (int k0 = 0; k0 < 1024; k0 += 32) {
    __syncthreads();
#pragma unroll
    for (int j = 0; j < 2; ++j) {
      __builtin_amdgcn_global_load_lds((gbl_void*)(gA + (size_t)(16 * j) * 1024 + k0),
                                       (lds_void*)(lA + 16 * j * 32), 16, 0, 0);
      __builtin_amdgcn_global_load_lds((gbl_void*)(gB + (size_t)(16 * j) * 1024 + k0),
                                       (lds_void*)(lB + 16 * j * 32), 16, 0, 0);
    }
    __syncthreads();
    bf16x8 af[4], bfr[4];
#pragma unroll
    for (int i = 0; i < 4; ++i)
      af[i] = *(const bf16x8*)&As[(64 * wr + 16 * i + lrow) * 32 + 8 * quad];
#pragma unroll
    for (int j = 0; j < 4; ++j)
      bfr[j] = *(const bf16x8*)&Bs[(64 * wc + 16 * j + lrow) * 32 + 8 * quad];
#pragma unroll
    for (int i = 0; i < 4; ++i)
#pragma unroll
      for (int j = 0; j < 4; ++j)
        acc[i][j] = __builtin_amdgcn_mfma_f32_16x16x32_bf16(af[i], bfr[j], acc[i][j], 0, 0, 0);
  }

  float bv[4];
#pragma unroll
  for (int j = 0; j < 4; ++j) bv[j] = bf2f(bi[n0 + 64 * wc + 16 * j + lrow]);
#pragma unroll
  for (int i = 0; i < 4; ++i) {
    int row = m0 + 64 * wr + 16 * i + 4 * quad;
#pragma unroll
    for (int j = 0; j < 4; ++j) {
      int col = n0 + 64 * wc + 16 * j + lrow;
#pragma unroll
      for (int r = 0; r < 4; ++r)
        C[(size_t)(row + r) * 1024 + col] = acc[i][j][r] + bv[j];
    }
  }
}

extern "C" void kernel_launch(void* const* d_in, const int* in_sizes, int n_in,
                              void* d_out, int out_size, void* d_ws, size_t ws_size,
                              hipStream_t stream) {
  (void)in_sizes; (void)n_in; (void)out_size; (void)ws_size;
  const size_t M1 = 1048576u;
  u16* ws = (u16*)d_ws;
  u16* wtA   = ws;             // [2048,1024] concat(Wa_qk^T*0.125, Wa_v^T)
  u16* wtB   = ws + 2 * M1;    // [2048,1024] concat(Wb_qk^T, Wb_v^T)
  u16* wtO   = ws + 4 * M1;    // [2048,1024] concat(Wa_o^T, Wb_o^T)
  u16* biasQ = ws + 6 * M1;    // [2,2048]
  u16* biasO = ws + 6 * M1 + 4096;  // [2,1024]
  u16* ab    = ws + 7 * M1;    // [2][4096,1024] bf16 inputs (dead after QKV)
  u16* vt    = ab;             // alias: [2][bh][64][2048]
  u16* qkbuf = ws + 15 * M1;   // [2][bh][2048][64]
  u16* vbuf  = ws + 23 * M1;   // [2][bh][2048][64] (dead after transpose_v)
  u16* ctx   = vbuf;           // alias: [2][4096,1024]

  dim3 blk(256);
  k_cvt_in<<<dim3(2048, 2), blk, 0, stream>>>((const float*)d_in[0],
                                              (const float*)d_in[1], ab);
  k_cvt_bias<<<dim3(4, 6), blk, 0, stream>>>(
      (const float*)d_in[3], (const float*)d_in[5], (const float*)d_in[7],
      (const float*)d_in[9], (const float*)d_in[11], (const float*)d_in[13], biasQ);
  k_transpose_w<<<dim3(16, 16, 6), blk, 0, stream>>>(
      (const float*)d_in[2], (const float*)d_in[4], (const float*)d_in[6],
      (const float*)d_in[8], (const float*)d_in[10], (const float*)d_in[12],
      wtA, wtA + M1, wtB, wtB + M1, wtO, wtO + M1);
  k_gemm_qkv<<<dim3(16, 32, 2), blk, 0, stream>>>(ab, wtA, wtB, biasQ, qkbuf, vbuf);
  k_transpose_v<<<dim3(32, 64), blk, 0, stream>>>(vbuf, vt);
  k_attn<<<dim3(32, 16, 2), blk, 0, stream>>>(qkbuf, vt, ctx);
  k_gemm_o<<<dim3(8, 32, 2), blk, 0, stream>>>(ctx, wtO, biasO, (float*)d_out);
}